// Round 1
// baseline (2785.266 us; speedup 1.0000x reference)
//
#include <hip/hip_runtime.h>

#define LSZ   16
#define NBATCH 2
#define NSITE (NBATCH*LSZ*LSZ*LSZ*LSZ)   // 131072
#define NIN   10
#define NOUT  8
#define ND    4
#define NCPLX ((long)NSITE * NOUT * 9)   // 9,437,184 complex output elements
#define NLINE_PER_DIR (NSITE / LSZ)      // 8192
#define NLINK (NSITE * ND)               // 524288
#define WSTRIDE 108                      // u32 per site in LDS image: 9 e * 12 ch (10 used)

typedef unsigned int u32;

struct M3 { float re[9]; float im[9]; };

// bf16 pack helpers: u32 = bf16(lo) | bf16(hi)<<16
__device__ __forceinline__ unsigned short f2bf(float x) {
    u32 u = __float_as_uint(x);
    u32 r = (u + 0x7fffu + ((u >> 16) & 1u)) >> 16;   // RNE
    return (unsigned short)r;
}
__device__ __forceinline__ u32 packbf(float lo, float hi) {
    return (u32)f2bf(lo) | ((u32)f2bf(hi) << 16);
}

#if __has_builtin(__builtin_amdgcn_fdot2_f32_bf16)
#define CONV_DOT2 1
typedef __bf16 bf16x2 __attribute__((ext_vector_type(2)));
__device__ __forceinline__ bf16x2 as_b2(u32 v) {
    union { u32 u; bf16x2 b; } x; x.u = v; return x.b;
}
__device__ __forceinline__ void cdot(u32 w, u32 oa, u32 ob, float& sr, float& si) {
    sr = __builtin_amdgcn_fdot2_f32_bf16(as_b2(w), as_b2(oa), sr, false);
    si = __builtin_amdgcn_fdot2_f32_bf16(as_b2(w), as_b2(ob), si, false);
}
#else
#define CONV_DOT2 0
// scalar fallback used inside conv loop below
#endif

__device__ __forceinline__ void loadM2(M3& m, const float2* __restrict__ U2, long link) {
    const float2* p = U2 + link * 9;
#pragma unroll
    for (int e = 0; e < 9; e++) { float2 v = p[e]; m.re[e] = v.x; m.im[e] = v.y; }
}

// o = a * b
__device__ __forceinline__ void mulM(M3& o, const M3& a, const M3& b) {
#pragma unroll
    for (int r = 0; r < 3; r++) {
#pragma unroll
        for (int c = 0; c < 3; c++) {
            float xr = 0.f, xi = 0.f;
#pragma unroll
            for (int k = 0; k < 3; k++) {
                float ar = a.re[r*3+k], ai = a.im[r*3+k];
                float br = b.re[k*3+c], bi = b.im[k*3+c];
                xr = fmaf(ar, br, xr); xr = fmaf(-ai, bi, xr);
                xi = fmaf(ar, bi, xi); xi = fmaf(ai, br, xi);
            }
            o.re[r*3+c] = xr; o.im[r*3+c] = xi;
        }
    }
}

// o = a * b^H
__device__ __forceinline__ void mulAdjM(M3& o, const M3& a, const M3& b) {
#pragma unroll
    for (int r = 0; r < 3; r++) {
#pragma unroll
        for (int c = 0; c < 3; c++) {
            float xr = 0.f, xi = 0.f;
#pragma unroll
            for (int k = 0; k < 3; k++) {
                float ar = a.re[r*3+k], ai = a.im[r*3+k];
                float br = b.re[c*3+k], bi = b.im[c*3+k];
                xr = fmaf(ar, br, xr); xr = fmaf(ai, bi, xr);
                xi = fmaf(ai, br, xi); xi = fmaf(-ar, bi, xi);
            }
            o.re[r*3+c] = xr; o.im[r*3+c] = xi;
        }
    }
}

// site s = b*65536 + x*4096 + y*256 + z*16 + t ; mu: 0->x,1->y,2->z,3->t
__device__ __forceinline__ int shift_site(int s, int mu, int k) {
    int sh = 12 - 4 * mu;
    int c  = (s >> sh) & 15;
    int nc = (c + k) & 15;
    return (s & ~(15 << sh)) | (nc << sh);
}

// ---------------- Kernel 1: Polyakov loops -> compact T (reads planar U) -----
__global__ __launch_bounds__(256) void poly_kernel(const float* __restrict__ Ure,
                                                   const float* __restrict__ Uim,
                                                   u32* __restrict__ T) {
    __shared__ float2 sm[16 * 145];   // 18.56 KB

    int line0 = blockIdx.x * 16;
    int mu    = line0 / NLINE_PER_DIR;
    int lidx0 = line0 - mu * NLINE_PER_DIR;
    int sh    = 12 - 4 * mu;
    int low0  = lidx0 & ((1 << sh) - 1);
    int high0 = lidx0 >> sh;
    int s_base0 = (high0 << (sh + 4)) | low0;

    for (int n = threadIdx.x; n < 16 * 16 * 9; n += 256) {
        int siteIdx = n / 9;
        int e       = n - siteIdx * 9;
        int site, l, c;
        if (mu == 3) { site = (lidx0 << 4) + siteIdx; l = siteIdx >> 4; c = siteIdx & 15; }
        else         { site = s_base0 + ((siteIdx >> 4) << sh) + (siteIdx & 15);
                       l = siteIdx & 15; c = siteIdx >> 4; }
        long g = ((long)site * 4 + mu) * 9 + e;
        sm[l * 145 + c * 9 + e] = make_float2(Ure[g], Uim[g]);
    }
    __syncthreads();

    int c = threadIdx.x & 15;
    int l = threadIdx.x >> 4;

    M3 P;
    {
        const float2* m0 = &sm[l * 145 + c * 9];
#pragma unroll
        for (int e = 0; e < 9; e++) { float2 v = m0[e]; P.re[e] = v.x; P.im[e] = v.y; }
    }
    for (int step = 1; step < LSZ; step++) {
        const float2* mn = &sm[l * 145 + ((c + step) & 15) * 9];
        M3 Un, Tm;
#pragma unroll
        for (int e = 0; e < 9; e++) { float2 v = mn[e]; Un.re[e] = v.x; Un.im[e] = v.y; }
        mulM(Tm, P, Un);
        P = Tm;
    }

    int line_global = line0 + l;
    u32* Tp = T + ((long)line_global * 9) * 16 + c;
#pragma unroll
    for (int e = 0; e < 9; e++) Tp[e * 16] = packbf(P.re[e], P.im[e]);
}

// ------- Kernel 2: plaquettes + merge-poly -> W planes; also emits U2 --------
// W layout: 27 planes of NSITE uint4. Plane p=(e*3+q); uint4 = j-slots 4q..4q+3
// (j=10,11 zero). Block writes 32 consecutive uint4 per plane -> coalesced.
// LDS: sU (37.9 KB) and sw (13.8 KB) are time-disjoint -> union them.
// Occupancy 3 -> 4 blocks/CU (latency-bound kernel).
__global__ __launch_bounds__(192) void plaq_merge_kernel(const float* __restrict__ Ure,
                                                         const float* __restrict__ Uim,
                                                         const u32* __restrict__ T,
                                                         u32* __restrict__ W,
                                                         float2* __restrict__ U2) {
    __shared__ __align__(16) char smem[4 * 32 * 37 * sizeof(float2)];   // 37,888 B
    float2* sU = (float2*)smem;      // live: stage .. P compute
    u32*    sw = (u32*)smem;         // live: after barrier .. W4 write (13,824 B)

    int s0 = blockIdx.x * 32;

    for (int n = threadIdx.x; n < 8 * 16 * 36; n += 192) {
        int run = n / 576;
        int q   = n - run * 576;
        int sir = q / 36;
        int e36 = q - sir * 36;
        int slot = run >> 1, r = run & 1;
        int base = s0 + r * 16;
        if (slot < 3) base = shift_site(base, slot, 1);
        long g = (long)(base + sir) * 36 + e36;
        sU[(slot * 32 + r * 16 + sir) * 37 + e36] = make_float2(Ure[g], Uim[g]);
    }
    __syncthreads();

    // repack byproduct: write U2 for this block's 32 sites from the self slot
    for (int n = threadIdx.x; n < 32 * 36; n += 192) {
        int sir = n / 36;
        int e36 = n - sir * 36;
        U2[(long)(s0 + sir) * 36 + e36] = sU[(3 * 32 + sir) * 37 + e36];
    }

    int p  = threadIdx.x >> 5;
    int ls = threadIdx.x & 31;

    int mu = (p < 3) ? 0 : ((p < 5) ? 1 : 2);
    int nu = (mu == 0) ? (p + 1) : ((mu == 1) ? (p - 1) : 3);

    M3 Umu, Unu, Unu_f, Umu_f, T1, T2, P;
    {
        const float2* pp;
#define LDM(m, slot, site, link) \
        pp = &sU[((slot) * 32 + (site)) * 37 + (link) * 9]; \
        _Pragma("unroll") \
        for (int e = 0; e < 9; e++) { float2 v = pp[e]; (m).re[e] = v.x; (m).im[e] = v.y; }

        LDM(Umu, 3, ls, mu);
        LDM(Unu, 3, ls, nu);
        LDM(Unu_f, mu, ls, nu);
        int lsrot = (ls & 16) | ((ls + 1) & 15);
        int fslot = (nu == 3) ? 3 : nu;
        int fsite = (nu == 3) ? lsrot : ls;
        LDM(Umu_f, fslot, fsite, mu);
#undef LDM
    }

    mulM(T1, Umu, Unu_f);
    mulAdjM(T2, T1, Umu_f);
    mulAdjM(P, T2, Unu);

    // all sU reads are done (P, U2 repack); reuse the LDS as sw
    __syncthreads();

#pragma unroll
    for (int e = 0; e < 9; e++) sw[ls * WSTRIDE + e * 12 + p] = packbf(P.re[e], P.im[e]);

    // pad j-slots 10,11 zeroed
    for (int it = threadIdx.x; it < 32 * 9 * 2; it += 192) {
        int site = it / 18;
        int r    = it - site * 18;
        sw[site * WSTRIDE + (r >> 1) * 12 + 10 + (r & 1)] = 0u;
    }

    for (int it = threadIdx.x; it < 32 * 4 * 9; it += 192) {
        int ls2 = it / 36;
        int r   = it - ls2 * 36;
        int mu2 = r / 9;
        int e2  = r - mu2 * 9;
        int s2  = s0 + ls2;
        int sh  = 12 - 4 * mu2;
        int c   = (s2 >> sh) & 15;
        int low = s2 & ((1 << sh) - 1);
        int rest = s2 >> (sh + 4);
        int lidx = (rest << sh) | low;
        long lg  = (long)mu2 * NLINE_PER_DIR + lidx;
        sw[ls2 * WSTRIDE + e2 * 12 + 6 + mu2] = T[(lg * 9 + e2) * 16 + c];
    }
    __syncthreads();

    // plane-transposed write: 27 planes x 32 consecutive uint4
    uint4* W4 = (uint4*)W;
    for (int it = threadIdx.x; it < 27 * 32; it += 192) {
        int pl  = it >> 5;
        int ls2 = it & 31;
        int e   = pl / 3, q = pl - e * 3;
        const uint4 v = *(const uint4*)(sw + ls2 * WSTRIDE + e * 12 + q * 4);
        W4[(long)pl * NSITE + s0 + ls2] = v;
    }
}

// ---------------- Kernel 3: gauge-equivariant conv (plane-W, i-paired) -------
// Wave = 16 consecutive-t sites x 4 lane-groups; lane group i0 handles output
// channels i0 and i0+4. Per (mu,kk): 27 plane loads of 16 consecutive uint4
// (256 B, 4-way broadcast -> ~2 L1 lines/instr).
// LDS: som (7.5 KB, live during loop) unioned with sout (18 KB, live after
// loop) -> 18.4 KB/block -> 7-8 blocks/CU (was 26.1 KB -> low occupancy,
// 57% VALUBusy = latency-bound). XCD swizzle: 2048 blocks % 8 == 0, chunk
// of 256 consecutive blocks per XCD keeps x-stencil (+-64 blocks) reuse in
// the same L2.
template <int MODE>
__global__ __launch_bounds__(256, 7) void conv_kernel(const float2* __restrict__ U2,
                                                      const u32* __restrict__ W,
                                                      const float* __restrict__ omre,
                                                      const float* __restrict__ omim,
                                                      float* __restrict__ out) {
    __shared__ __align__(16) char smraw[64 * 72 * sizeof(float)];   // 18,432 B
    uint2* som  = (uint2*)smraw;   // 12*NIN*8 uint2 = 7,680 B, live during loop
    float* sout = (float*)smraw;   // 18,432 B, live after loop (MODE 2)

    for (int t = threadIdx.x; t < 12 * NIN * 8; t += blockDim.x) {
        int i  = t & 7;
        int j  = (t >> 3) % NIN;
        int mk = (t >> 3) / NIN;
        int mu = mk / 3, kk = mk % 3;
        int oidx = ((i * NIN + j) * ND + mu) * 3 + kk;
        float orv = omre[oidx], oiv = omim[oidx];
        som[t] = make_uint2(packbf(orv, -oiv), packbf(oiv, orv));
    }
    __syncthreads();

    // XCD-aware bijective swizzle (gridDim.x = 2048, divisible by 8)
    int nxcd  = 8;
    int chunk = gridDim.x >> 3;
    int lb    = ((int)blockIdx.x & (nxcd - 1)) * chunk + ((int)blockIdx.x >> 3);

    int lane = threadIdx.x & 63;
    int wv   = threadIdx.x >> 6;
    int t    = lane & 15;                 // position in t-line
    int i0   = lane >> 4;                 // 0..3; handles i0, i0+4
    int s0b  = lb * 64;
    int sline = s0b + wv * 16;            // wave's t-line base (16-aligned)
    int s    = sline + t;

    const uint4* W4 = (const uint4*)W;

    float accr[2][9], acci[2][9];
#pragma unroll
    for (int p2 = 0; p2 < 2; p2++)
#pragma unroll
        for (int e = 0; e < 9; e++) { accr[p2][e] = 0.f; acci[p2][e] = 0.f; }

    for (int mu = 0; mu < ND; mu++) {
        float mr[2][9], mi[2][9];
#pragma unroll
        for (int p2 = 0; p2 < 2; p2++)
#pragma unroll
            for (int e = 0; e < 9; e++) { mr[p2][e] = 0.f; mi[p2][e] = 0.f; }

        for (int kk = 0; kk < 3; kk++) {
            int nb;
            if (mu < 3) nb = shift_site(s, mu, kk - 1);
            else        nb = sline + ((t + kk - 1) & 15);

            int mk = mu * 3 + kk;
            u32 oa0[NIN], ob0[NIN], oa1[NIN], ob1[NIN];
#pragma unroll
            for (int j = 0; j < NIN; j++) {
                uint2 v0 = som[(mk * NIN + j) * 8 + i0];
                uint2 v1 = som[(mk * NIN + j) * 8 + i0 + 4];
                oa0[j] = v0.x; ob0[j] = v0.y;
                oa1[j] = v1.x; ob1[j] = v1.y;
            }

#pragma unroll
            for (int g = 0; g < 3; g++) {           // e-triple: 9 plane loads
                uint4 w[9];
#pragma unroll
                for (int q = 0; q < 9; q++) w[q] = W4[(long)(g * 9 + q) * NSITE + nb];
#pragma unroll
                for (int ee = 0; ee < 3; ee++) {
                    int e = g * 3 + ee;
                    uint4 a  = w[ee * 3 + 0];
                    uint4 b  = w[ee * 3 + 1];
                    uint4 cv = w[ee * 3 + 2];
                    float sr0 = mr[0][e], si0 = mi[0][e];
                    float sr1 = mr[1][e], si1 = mi[1][e];
#if CONV_DOT2
                    cdot(a.x,  oa0[0], ob0[0], sr0, si0); cdot(a.x,  oa1[0], ob1[0], sr1, si1);
                    cdot(a.y,  oa0[1], ob0[1], sr0, si0); cdot(a.y,  oa1[1], ob1[1], sr1, si1);
                    cdot(a.z,  oa0[2], ob0[2], sr0, si0); cdot(a.z,  oa1[2], ob1[2], sr1, si1);
                    cdot(a.w,  oa0[3], ob0[3], sr0, si0); cdot(a.w,  oa1[3], ob1[3], sr1, si1);
                    cdot(b.x,  oa0[4], ob0[4], sr0, si0); cdot(b.x,  oa1[4], ob1[4], sr1, si1);
                    cdot(b.y,  oa0[5], ob0[5], sr0, si0); cdot(b.y,  oa1[5], ob1[5], sr1, si1);
                    cdot(b.z,  oa0[6], ob0[6], sr0, si0); cdot(b.z,  oa1[6], ob1[6], sr1, si1);
                    cdot(b.w,  oa0[7], ob0[7], sr0, si0); cdot(b.w,  oa1[7], ob1[7], sr1, si1);
                    cdot(cv.x, oa0[8], ob0[8], sr0, si0); cdot(cv.x, oa1[8], ob1[8], sr1, si1);
                    cdot(cv.y, oa0[9], ob0[9], sr0, si0); cdot(cv.y, oa1[9], ob1[9], sr1, si1);
#else
                    u32 ws[NIN] = {a.x, a.y, a.z, a.w, b.x, b.y, b.z, b.w, cv.x, cv.y};
#pragma unroll
                    for (int j = 0; j < NIN; j++) {
                        float wr = __uint_as_float(ws[j] << 16);
                        float wi = __uint_as_float(ws[j] & 0xffff0000u);
                        float o0r = __uint_as_float(oa0[j] << 16), o0i = __uint_as_float(ob0[j] << 16);
                        float o1r = __uint_as_float(oa1[j] << 16), o1i = __uint_as_float(ob1[j] << 16);
                        // oa = (or, -oi) packed, ob = (oi, or) packed
                        float n0i = __uint_as_float(oa0[j] & 0xffff0000u);
                        float n1i = __uint_as_float(oa1[j] & 0xffff0000u);
                        float p0r = __uint_as_float(ob0[j] & 0xffff0000u);
                        float p1r = __uint_as_float(ob1[j] & 0xffff0000u);
                        sr0 = fmaf(o0r, wr, sr0); sr0 = fmaf(n0i, wi, sr0);
                        si0 = fmaf(o0i, wr, si0); si0 = fmaf(p0r, wi, si0);
                        sr1 = fmaf(o1r, wr, sr1); sr1 = fmaf(n1i, wi, sr1);
                        si1 = fmaf(o1i, wr, si1); si1 = fmaf(p1r, wi, si1);
                    }
#endif
                    mr[0][e] = sr0; mi[0][e] = si0;
                    mr[1][e] = sr1; mi[1][e] = si1;
                }
            }
        }

        // epilogue: out += A * Msum * A^H  (f32), for both i channels
        M3 A;
        loadM2(A, U2, (long)s * 4 + mu);
#pragma unroll
        for (int p2 = 0; p2 < 2; p2++) {
            M3 Tm;
#pragma unroll
            for (int r = 0; r < 3; r++) {
#pragma unroll
                for (int c = 0; c < 3; c++) {
                    float xr = 0.f, xi = 0.f;
#pragma unroll
                    for (int k = 0; k < 3; k++) {
                        float ar = A.re[r*3+k], ai = A.im[r*3+k];
                        float br = mr[p2][k*3+c], bi = mi[p2][k*3+c];
                        xr = fmaf(ar, br, xr); xr = fmaf(-ai, bi, xr);
                        xi = fmaf(ar, bi, xi); xi = fmaf(ai, br, xi);
                    }
                    Tm.re[r*3+c] = xr; Tm.im[r*3+c] = xi;
                }
            }
#pragma unroll
            for (int r = 0; r < 3; r++) {
#pragma unroll
                for (int c = 0; c < 3; c++) {
                    float xr = 0.f, xi = 0.f;
#pragma unroll
                    for (int k = 0; k < 3; k++) {
                        float ar = Tm.re[r*3+k], ai = Tm.im[r*3+k];
                        float br = A.re[c*3+k], bi = A.im[c*3+k];
                        xr = fmaf(ar, br, xr); xr = fmaf(ai, bi, xr);
                        if (MODE != 2) { xi = fmaf(ai, br, xi); xi = fmaf(-ar, bi, xi); }
                    }
                    accr[p2][r*3+c] += xr;
                    if (MODE != 2) acci[p2][r*3+c] += xi;
                }
            }
        }
    }

    if (MODE == 2) {
        // som is dead now; wait for all waves' loop reads before aliasing
        __syncthreads();
#pragma unroll
        for (int p2 = 0; p2 < 2; p2++) {
            int i = i0 + p2 * 4;
#pragma unroll
            for (int e = 0; e < 9; e++)
                sout[((wv * 16 + t) * 8 + i) * 9 + e] = accr[p2][e];
        }
        __syncthreads();
        long base = (long)lb * 4608;
        for (int n = threadIdx.x; n < 4608; n += 256) out[base + n] = sout[n];
    } else if (MODE == 0) {
#pragma unroll
        for (int p2 = 0; p2 < 2; p2++) {
            int i = i0 + p2 * 4;
            long cb = ((long)s * 8 + i) * 9;
            float2* op = (float2*)(out + cb * 2);
#pragma unroll
            for (int e = 0; e < 9; e++) op[e] = make_float2(accr[p2][e], acci[p2][e]);
        }
    } else {
#pragma unroll
        for (int p2 = 0; p2 < 2; p2++) {
            int i = i0 + p2 * 4;
            long cb = ((long)s * 8 + i) * 9;
#pragma unroll
            for (int e = 0; e < 9; e++) {
                out[cb + e]         = accr[p2][e];
                out[NCPLX + cb + e] = acci[p2][e];
            }
        }
    }
}

extern "C" void kernel_launch(void* const* d_in, const int* in_sizes, int n_in,
                              void* d_out, int out_size, void* d_ws, size_t ws_size,
                              hipStream_t stream) {
    const float* Ure  = (const float*)d_in[0];
    const float* Uim  = (const float*)d_in[1];
    const float* omre = (const float*)d_in[2];
    const float* omim = (const float*)d_in[3];
    float* out = (float*)d_out;

    const size_t wBytes  = (size_t)NSITE * WSTRIDE * sizeof(u32);   // 56.6 MB (27 planes)
    const size_t u2Bytes = (size_t)NLINK * 9 * sizeof(float2);      // 37.7 MB
    if (ws_size < wBytes + u2Bytes) return;

    u32*    W  = (u32*)d_ws;
    float2* U2 = (float2*)((char*)d_ws + wBytes);
    u32*    T  = (u32*)d_out;   // 18.9 MB temp in d_out; overwritten by conv

    poly_kernel<<<NSITE * 4 / (16 * 16), 256, 0, stream>>>(Ure, Uim, T);
    plaq_merge_kernel<<<NSITE / 32, 192, 0, stream>>>(Ure, Uim, T, W, U2);

    const int convGrid = NSITE * 4 / 256;   // 2048 blocks, 64 sites each
    if (out_size == (int)NCPLX)
        conv_kernel<2><<<convGrid, 256, 0, stream>>>(U2, W, omre, omim, out);
    else if (out_size == (int)(2 * NCPLX))
        conv_kernel<1><<<convGrid, 256, 0, stream>>>(U2, W, omre, omim, out);
    else
        conv_kernel<0><<<convGrid, 256, 0, stream>>>(U2, W, omre, omim, out);
}

// Round 2
// 301.545 us; speedup vs baseline: 9.2366x; 9.2366x over previous
//
#include <hip/hip_runtime.h>

#define LSZ   16
#define NBATCH 2
#define NSITE (NBATCH*LSZ*LSZ*LSZ*LSZ)   // 131072
#define NIN   10
#define NOUT  8
#define ND    4
#define NCPLX ((long)NSITE * NOUT * 9)   // 9,437,184 complex output elements
#define NLINE_PER_DIR (NSITE / LSZ)      // 8192
#define NLINK (NSITE * ND)               // 524288
#define WSTRIDE 108                      // u32 per site in LDS image: 9 e * 12 ch (10 used)

typedef unsigned int u32;

struct M3 { float re[9]; float im[9]; };

// bf16 pack helpers: u32 = bf16(lo) | bf16(hi)<<16
__device__ __forceinline__ unsigned short f2bf(float x) {
    u32 u = __float_as_uint(x);
    u32 r = (u + 0x7fffu + ((u >> 16) & 1u)) >> 16;   // RNE
    return (unsigned short)r;
}
__device__ __forceinline__ u32 packbf(float lo, float hi) {
    return (u32)f2bf(lo) | ((u32)f2bf(hi) << 16);
}

#if __has_builtin(__builtin_amdgcn_fdot2_f32_bf16)
#define CONV_DOT2 1
typedef __bf16 bf16x2 __attribute__((ext_vector_type(2)));
__device__ __forceinline__ bf16x2 as_b2(u32 v) {
    union { u32 u; bf16x2 b; } x; x.u = v; return x.b;
}
__device__ __forceinline__ void cdot(u32 w, u32 oa, u32 ob, float& sr, float& si) {
    sr = __builtin_amdgcn_fdot2_f32_bf16(as_b2(w), as_b2(oa), sr, false);
    si = __builtin_amdgcn_fdot2_f32_bf16(as_b2(w), as_b2(ob), si, false);
}
#else
#define CONV_DOT2 0
// scalar fallback used inside conv loop below
#endif

__device__ __forceinline__ void loadM2(M3& m, const float2* __restrict__ U2, long link) {
    const float2* p = U2 + link * 9;
#pragma unroll
    for (int e = 0; e < 9; e++) { float2 v = p[e]; m.re[e] = v.x; m.im[e] = v.y; }
}

// o = a * b
__device__ __forceinline__ void mulM(M3& o, const M3& a, const M3& b) {
#pragma unroll
    for (int r = 0; r < 3; r++) {
#pragma unroll
        for (int c = 0; c < 3; c++) {
            float xr = 0.f, xi = 0.f;
#pragma unroll
            for (int k = 0; k < 3; k++) {
                float ar = a.re[r*3+k], ai = a.im[r*3+k];
                float br = b.re[k*3+c], bi = b.im[k*3+c];
                xr = fmaf(ar, br, xr); xr = fmaf(-ai, bi, xr);
                xi = fmaf(ar, bi, xi); xi = fmaf(ai, br, xi);
            }
            o.re[r*3+c] = xr; o.im[r*3+c] = xi;
        }
    }
}

// o = a * b^H
__device__ __forceinline__ void mulAdjM(M3& o, const M3& a, const M3& b) {
#pragma unroll
    for (int r = 0; r < 3; r++) {
#pragma unroll
        for (int c = 0; c < 3; c++) {
            float xr = 0.f, xi = 0.f;
#pragma unroll
            for (int k = 0; k < 3; k++) {
                float ar = a.re[r*3+k], ai = a.im[r*3+k];
                float br = b.re[c*3+k], bi = b.im[c*3+k];
                xr = fmaf(ar, br, xr); xr = fmaf(ai, bi, xr);
                xi = fmaf(ai, br, xi); xi = fmaf(-ar, bi, xi);
            }
            o.re[r*3+c] = xr; o.im[r*3+c] = xi;
        }
    }
}

// site s = b*65536 + x*4096 + y*256 + z*16 + t ; mu: 0->x,1->y,2->z,3->t
__device__ __forceinline__ int shift_site(int s, int mu, int k) {
    int sh = 12 - 4 * mu;
    int c  = (s >> sh) & 15;
    int nc = (c + k) & 15;
    return (s & ~(15 << sh)) | (nc << sh);
}

// ---------------- Kernel 1: Polyakov loops -> compact T (reads planar U) -----
__global__ __launch_bounds__(256) void poly_kernel(const float* __restrict__ Ure,
                                                   const float* __restrict__ Uim,
                                                   u32* __restrict__ T) {
    __shared__ float2 sm[16 * 145];   // 18.56 KB

    int line0 = blockIdx.x * 16;
    int mu    = line0 / NLINE_PER_DIR;
    int lidx0 = line0 - mu * NLINE_PER_DIR;
    int sh    = 12 - 4 * mu;
    int low0  = lidx0 & ((1 << sh) - 1);
    int high0 = lidx0 >> sh;
    int s_base0 = (high0 << (sh + 4)) | low0;

    for (int n = threadIdx.x; n < 16 * 16 * 9; n += 256) {
        int siteIdx = n / 9;
        int e       = n - siteIdx * 9;
        int site, l, c;
        if (mu == 3) { site = (lidx0 << 4) + siteIdx; l = siteIdx >> 4; c = siteIdx & 15; }
        else         { site = s_base0 + ((siteIdx >> 4) << sh) + (siteIdx & 15);
                       l = siteIdx & 15; c = siteIdx >> 4; }
        long g = ((long)site * 4 + mu) * 9 + e;
        sm[l * 145 + c * 9 + e] = make_float2(Ure[g], Uim[g]);
    }
    __syncthreads();

    int c = threadIdx.x & 15;
    int l = threadIdx.x >> 4;

    M3 P;
    {
        const float2* m0 = &sm[l * 145 + c * 9];
#pragma unroll
        for (int e = 0; e < 9; e++) { float2 v = m0[e]; P.re[e] = v.x; P.im[e] = v.y; }
    }
    for (int step = 1; step < LSZ; step++) {
        const float2* mn = &sm[l * 145 + ((c + step) & 15) * 9];
        M3 Un, Tm;
#pragma unroll
        for (int e = 0; e < 9; e++) { float2 v = mn[e]; Un.re[e] = v.x; Un.im[e] = v.y; }
        mulM(Tm, P, Un);
        P = Tm;
    }

    int line_global = line0 + l;
    u32* Tp = T + ((long)line_global * 9) * 16 + c;
#pragma unroll
    for (int e = 0; e < 9; e++) Tp[e * 16] = packbf(P.re[e], P.im[e]);
}

// ------- Kernel 2: plaquettes + merge-poly -> W planes; also emits U2 --------
// W layout: 27 planes of NSITE uint4. Plane p=(e*3+q); uint4 = j-slots 4q..4q+3
// (j=10,11 zero). Block writes 32 consecutive uint4 per plane -> coalesced.
// LDS: sU (37.9 KB) and sw (13.8 KB) are time-disjoint -> union them.
__global__ __launch_bounds__(192) void plaq_merge_kernel(const float* __restrict__ Ure,
                                                         const float* __restrict__ Uim,
                                                         const u32* __restrict__ T,
                                                         u32* __restrict__ W,
                                                         float2* __restrict__ U2) {
    __shared__ __align__(16) char smem[4 * 32 * 37 * sizeof(float2)];   // 37,888 B
    float2* sU = (float2*)smem;      // live: stage .. P compute
    u32*    sw = (u32*)smem;         // live: after barrier .. W4 write (13,824 B)

    int s0 = blockIdx.x * 32;

    for (int n = threadIdx.x; n < 8 * 16 * 36; n += 192) {
        int run = n / 576;
        int q   = n - run * 576;
        int sir = q / 36;
        int e36 = q - sir * 36;
        int slot = run >> 1, r = run & 1;
        int base = s0 + r * 16;
        if (slot < 3) base = shift_site(base, slot, 1);
        long g = (long)(base + sir) * 36 + e36;
        sU[(slot * 32 + r * 16 + sir) * 37 + e36] = make_float2(Ure[g], Uim[g]);
    }
    __syncthreads();

    // repack byproduct: write U2 for this block's 32 sites from the self slot
    for (int n = threadIdx.x; n < 32 * 36; n += 192) {
        int sir = n / 36;
        int e36 = n - sir * 36;
        U2[(long)(s0 + sir) * 36 + e36] = sU[(3 * 32 + sir) * 37 + e36];
    }

    int p  = threadIdx.x >> 5;
    int ls = threadIdx.x & 31;

    int mu = (p < 3) ? 0 : ((p < 5) ? 1 : 2);
    int nu = (mu == 0) ? (p + 1) : ((mu == 1) ? (p - 1) : 3);

    M3 Umu, Unu, Unu_f, Umu_f, T1, T2, P;
    {
        const float2* pp;
#define LDM(m, slot, site, link) \
        pp = &sU[((slot) * 32 + (site)) * 37 + (link) * 9]; \
        _Pragma("unroll") \
        for (int e = 0; e < 9; e++) { float2 v = pp[e]; (m).re[e] = v.x; (m).im[e] = v.y; }

        LDM(Umu, 3, ls, mu);
        LDM(Unu, 3, ls, nu);
        LDM(Unu_f, mu, ls, nu);
        int lsrot = (ls & 16) | ((ls + 1) & 15);
        int fslot = (nu == 3) ? 3 : nu;
        int fsite = (nu == 3) ? lsrot : ls;
        LDM(Umu_f, fslot, fsite, mu);
#undef LDM
    }

    mulM(T1, Umu, Unu_f);
    mulAdjM(T2, T1, Umu_f);
    mulAdjM(P, T2, Unu);

    // all sU reads are done (P, U2 repack); reuse the LDS as sw
    __syncthreads();

#pragma unroll
    for (int e = 0; e < 9; e++) sw[ls * WSTRIDE + e * 12 + p] = packbf(P.re[e], P.im[e]);

    // pad j-slots 10,11 zeroed
    for (int it = threadIdx.x; it < 32 * 9 * 2; it += 192) {
        int site = it / 18;
        int r    = it - site * 18;
        sw[site * WSTRIDE + (r >> 1) * 12 + 10 + (r & 1)] = 0u;
    }

    for (int it = threadIdx.x; it < 32 * 4 * 9; it += 192) {
        int ls2 = it / 36;
        int r   = it - ls2 * 36;
        int mu2 = r / 9;
        int e2  = r - mu2 * 9;
        int s2  = s0 + ls2;
        int sh  = 12 - 4 * mu2;
        int c   = (s2 >> sh) & 15;
        int low = s2 & ((1 << sh) - 1);
        int rest = s2 >> (sh + 4);
        int lidx = (rest << sh) | low;
        long lg  = (long)mu2 * NLINE_PER_DIR + lidx;
        sw[ls2 * WSTRIDE + e2 * 12 + 6 + mu2] = T[(lg * 9 + e2) * 16 + c];
    }
    __syncthreads();

    // plane-transposed write: 27 planes x 32 consecutive uint4
    uint4* W4 = (uint4*)W;
    for (int it = threadIdx.x; it < 27 * 32; it += 192) {
        int pl  = it >> 5;
        int ls2 = it & 31;
        int e   = pl / 3, q = pl - e * 3;
        const uint4 v = *(const uint4*)(sw + ls2 * WSTRIDE + e * 12 + q * 4);
        W4[(long)pl * NSITE + s0 + ls2] = v;
    }
}

// ---------------- Kernel 3: gauge-equivariant conv (plane-W, i-paired) -------
// Wave = 16 consecutive-t sites x 4 lane-groups; lane group i0 handles output
// channels i0 and i0+4. Per (mu,kk): 27 plane loads of 16 consecutive uint4
// (256 B, 4-way broadcast -> ~2 L1 lines/instr).
// LDS: som (7.5 KB, live during loop) unioned with sout (18 KB, live after
// loop) -> 18.4 KB/block -> LDS allows 8 blocks/CU; at the natural 72 VGPR
// the HW allows 7 waves/SIMD, so runtime occupancy floats up without any
// allocator cap. NOTE: __launch_bounds__(256,7) (round 1) forced VGPR 72->36
// and spilled the accumulators to scratch: 11.4 GB HBM traffic, 17x slower.
// Keep the min-waves arg at 3 (no register pressure).
template <int MODE>
__global__ __launch_bounds__(256, 3) void conv_kernel(const float2* __restrict__ U2,
                                                      const u32* __restrict__ W,
                                                      const float* __restrict__ omre,
                                                      const float* __restrict__ omim,
                                                      float* __restrict__ out) {
    __shared__ __align__(16) char smraw[64 * 72 * sizeof(float)];   // 18,432 B
    uint2* som  = (uint2*)smraw;   // 12*NIN*8 uint2 = 7,680 B, live during loop
    float* sout = (float*)smraw;   // 18,432 B, live after loop (MODE 2)

    for (int t = threadIdx.x; t < 12 * NIN * 8; t += blockDim.x) {
        int i  = t & 7;
        int j  = (t >> 3) % NIN;
        int mk = (t >> 3) / NIN;
        int mu = mk / 3, kk = mk % 3;
        int oidx = ((i * NIN + j) * ND + mu) * 3 + kk;
        float orv = omre[oidx], oiv = omim[oidx];
        som[t] = make_uint2(packbf(orv, -oiv), packbf(oiv, orv));
    }
    __syncthreads();

    // XCD-aware bijective swizzle (gridDim.x = 2048, divisible by 8)
    int nxcd  = 8;
    int chunk = gridDim.x >> 3;
    int lb    = ((int)blockIdx.x & (nxcd - 1)) * chunk + ((int)blockIdx.x >> 3);

    int lane = threadIdx.x & 63;
    int wv   = threadIdx.x >> 6;
    int t    = lane & 15;                 // position in t-line
    int i0   = lane >> 4;                 // 0..3; handles i0, i0+4
    int s0b  = lb * 64;
    int sline = s0b + wv * 16;            // wave's t-line base (16-aligned)
    int s    = sline + t;

    const uint4* W4 = (const uint4*)W;

    float accr[2][9], acci[2][9];
#pragma unroll
    for (int p2 = 0; p2 < 2; p2++)
#pragma unroll
        for (int e = 0; e < 9; e++) { accr[p2][e] = 0.f; acci[p2][e] = 0.f; }

    for (int mu = 0; mu < ND; mu++) {
        float mr[2][9], mi[2][9];
#pragma unroll
        for (int p2 = 0; p2 < 2; p2++)
#pragma unroll
            for (int e = 0; e < 9; e++) { mr[p2][e] = 0.f; mi[p2][e] = 0.f; }

        for (int kk = 0; kk < 3; kk++) {
            int nb;
            if (mu < 3) nb = shift_site(s, mu, kk - 1);
            else        nb = sline + ((t + kk - 1) & 15);

            int mk = mu * 3 + kk;
            u32 oa0[NIN], ob0[NIN], oa1[NIN], ob1[NIN];
#pragma unroll
            for (int j = 0; j < NIN; j++) {
                uint2 v0 = som[(mk * NIN + j) * 8 + i0];
                uint2 v1 = som[(mk * NIN + j) * 8 + i0 + 4];
                oa0[j] = v0.x; ob0[j] = v0.y;
                oa1[j] = v1.x; ob1[j] = v1.y;
            }

#pragma unroll
            for (int g = 0; g < 3; g++) {           // e-triple: 9 plane loads
                uint4 w[9];
#pragma unroll
                for (int q = 0; q < 9; q++) w[q] = W4[(long)(g * 9 + q) * NSITE + nb];
#pragma unroll
                for (int ee = 0; ee < 3; ee++) {
                    int e = g * 3 + ee;
                    uint4 a  = w[ee * 3 + 0];
                    uint4 b  = w[ee * 3 + 1];
                    uint4 cv = w[ee * 3 + 2];
                    float sr0 = mr[0][e], si0 = mi[0][e];
                    float sr1 = mr[1][e], si1 = mi[1][e];
#if CONV_DOT2
                    cdot(a.x,  oa0[0], ob0[0], sr0, si0); cdot(a.x,  oa1[0], ob1[0], sr1, si1);
                    cdot(a.y,  oa0[1], ob0[1], sr0, si0); cdot(a.y,  oa1[1], ob1[1], sr1, si1);
                    cdot(a.z,  oa0[2], ob0[2], sr0, si0); cdot(a.z,  oa1[2], ob1[2], sr1, si1);
                    cdot(a.w,  oa0[3], ob0[3], sr0, si0); cdot(a.w,  oa1[3], ob1[3], sr1, si1);
                    cdot(b.x,  oa0[4], ob0[4], sr0, si0); cdot(b.x,  oa1[4], ob1[4], sr1, si1);
                    cdot(b.y,  oa0[5], ob0[5], sr0, si0); cdot(b.y,  oa1[5], ob1[5], sr1, si1);
                    cdot(b.z,  oa0[6], ob0[6], sr0, si0); cdot(b.z,  oa1[6], ob1[6], sr1, si1);
                    cdot(b.w,  oa0[7], ob0[7], sr0, si0); cdot(b.w,  oa1[7], ob1[7], sr1, si1);
                    cdot(cv.x, oa0[8], ob0[8], sr0, si0); cdot(cv.x, oa1[8], ob1[8], sr1, si1);
                    cdot(cv.y, oa0[9], ob0[9], sr0, si0); cdot(cv.y, oa1[9], ob1[9], sr1, si1);
#else
                    u32 ws[NIN] = {a.x, a.y, a.z, a.w, b.x, b.y, b.z, b.w, cv.x, cv.y};
#pragma unroll
                    for (int j = 0; j < NIN; j++) {
                        float wr = __uint_as_float(ws[j] << 16);
                        float wi = __uint_as_float(ws[j] & 0xffff0000u);
                        float o0r = __uint_as_float(oa0[j] << 16), o0i = __uint_as_float(ob0[j] << 16);
                        float o1r = __uint_as_float(oa1[j] << 16), o1i = __uint_as_float(ob1[j] << 16);
                        // oa = (or, -oi) packed, ob = (oi, or) packed
                        float n0i = __uint_as_float(oa0[j] & 0xffff0000u);
                        float n1i = __uint_as_float(oa1[j] & 0xffff0000u);
                        float p0r = __uint_as_float(ob0[j] & 0xffff0000u);
                        float p1r = __uint_as_float(ob1[j] & 0xffff0000u);
                        sr0 = fmaf(o0r, wr, sr0); sr0 = fmaf(n0i, wi, sr0);
                        si0 = fmaf(o0i, wr, si0); si0 = fmaf(p0r, wi, si0);
                        sr1 = fmaf(o1r, wr, sr1); sr1 = fmaf(n1i, wi, sr1);
                        si1 = fmaf(o1i, wr, si1); si1 = fmaf(p1r, wi, si1);
                    }
#endif
                    mr[0][e] = sr0; mi[0][e] = si0;
                    mr[1][e] = sr1; mi[1][e] = si1;
                }
            }
        }

        // epilogue: out += A * Msum * A^H  (f32), for both i channels
        M3 A;
        loadM2(A, U2, (long)s * 4 + mu);
#pragma unroll
        for (int p2 = 0; p2 < 2; p2++) {
            M3 Tm;
#pragma unroll
            for (int r = 0; r < 3; r++) {
#pragma unroll
                for (int c = 0; c < 3; c++) {
                    float xr = 0.f, xi = 0.f;
#pragma unroll
                    for (int k = 0; k < 3; k++) {
                        float ar = A.re[r*3+k], ai = A.im[r*3+k];
                        float br = mr[p2][k*3+c], bi = mi[p2][k*3+c];
                        xr = fmaf(ar, br, xr); xr = fmaf(-ai, bi, xr);
                        xi = fmaf(ar, bi, xi); xi = fmaf(ai, br, xi);
                    }
                    Tm.re[r*3+c] = xr; Tm.im[r*3+c] = xi;
                }
            }
#pragma unroll
            for (int r = 0; r < 3; r++) {
#pragma unroll
                for (int c = 0; c < 3; c++) {
                    float xr = 0.f, xi = 0.f;
#pragma unroll
                    for (int k = 0; k < 3; k++) {
                        float ar = Tm.re[r*3+k], ai = Tm.im[r*3+k];
                        float br = A.re[c*3+k], bi = A.im[c*3+k];
                        xr = fmaf(ar, br, xr); xr = fmaf(ai, bi, xr);
                        if (MODE != 2) { xi = fmaf(ai, br, xi); xi = fmaf(-ar, bi, xi); }
                    }
                    accr[p2][r*3+c] += xr;
                    if (MODE != 2) acci[p2][r*3+c] += xi;
                }
            }
        }
    }

    if (MODE == 2) {
        // som is dead now; wait for all waves' loop reads before aliasing
        __syncthreads();
#pragma unroll
        for (int p2 = 0; p2 < 2; p2++) {
            int i = i0 + p2 * 4;
#pragma unroll
            for (int e = 0; e < 9; e++)
                sout[((wv * 16 + t) * 8 + i) * 9 + e] = accr[p2][e];
        }
        __syncthreads();
        long base = (long)lb * 4608;
        for (int n = threadIdx.x; n < 4608; n += 256) out[base + n] = sout[n];
    } else if (MODE == 0) {
#pragma unroll
        for (int p2 = 0; p2 < 2; p2++) {
            int i = i0 + p2 * 4;
            long cb = ((long)s * 8 + i) * 9;
            float2* op = (float2*)(out + cb * 2);
#pragma unroll
            for (int e = 0; e < 9; e++) op[e] = make_float2(accr[p2][e], acci[p2][e]);
        }
    } else {
#pragma unroll
        for (int p2 = 0; p2 < 2; p2++) {
            int i = i0 + p2 * 4;
            long cb = ((long)s * 8 + i) * 9;
#pragma unroll
            for (int e = 0; e < 9; e++) {
                out[cb + e]         = accr[p2][e];
                out[NCPLX + cb + e] = acci[p2][e];
            }
        }
    }
}

extern "C" void kernel_launch(void* const* d_in, const int* in_sizes, int n_in,
                              void* d_out, int out_size, void* d_ws, size_t ws_size,
                              hipStream_t stream) {
    const float* Ure  = (const float*)d_in[0];
    const float* Uim  = (const float*)d_in[1];
    const float* omre = (const float*)d_in[2];
    const float* omim = (const float*)d_in[3];
    float* out = (float*)d_out;

    const size_t wBytes  = (size_t)NSITE * WSTRIDE * sizeof(u32);   // 56.6 MB (27 planes)
    const size_t u2Bytes = (size_t)NLINK * 9 * sizeof(float2);      // 37.7 MB
    if (ws_size < wBytes + u2Bytes) return;

    u32*    W  = (u32*)d_ws;
    float2* U2 = (float2*)((char*)d_ws + wBytes);
    u32*    T  = (u32*)d_out;   // 18.9 MB temp in d_out; overwritten by conv

    poly_kernel<<<NSITE * 4 / (16 * 16), 256, 0, stream>>>(Ure, Uim, T);
    plaq_merge_kernel<<<NSITE / 32, 192, 0, stream>>>(Ure, Uim, T, W, U2);

    const int convGrid = NSITE * 4 / 256;   // 2048 blocks, 64 sites each
    if (out_size == (int)NCPLX)
        conv_kernel<2><<<convGrid, 256, 0, stream>>>(U2, W, omre, omim, out);
    else if (out_size == (int)(2 * NCPLX))
        conv_kernel<1><<<convGrid, 256, 0, stream>>>(U2, W, omre, omim, out);
    else
        conv_kernel<0><<<convGrid, 256, 0, stream>>>(U2, W, omre, omim, out);
}